// Round 11
// baseline (176.296 us; speedup 1.0000x reference)
//
#include <hip/hip_runtime.h>

// bf16 MFMA fragment types (gfx950): A/B = 8 bf16 (4 VGPR), C/D = 4 fp32
typedef __attribute__((ext_vector_type(8))) short bf16x8;
typedef __attribute__((ext_vector_type(4))) float f32x4;
typedef __attribute__((ext_vector_type(2))) unsigned int u32x2;
typedef __attribute__((ext_vector_type(4))) unsigned int u32x4;

#define LDSTR 136            // W1^T LDS leading dim (shorts): 128 + 8 pad
#define TPW 8                // (fallback) 16-edge tiles per wave

// f32 -> bf16 round-to-nearest-even
static __device__ __forceinline__ unsigned int pack2bf(float x, float y) {
  unsigned int ux = __builtin_bit_cast(unsigned int, x);
  ux += 0x7fffu + ((ux >> 16) & 1u);
  unsigned int uy = __builtin_bit_cast(unsigned int, y);
  uy += 0x7fffu + ((uy >> 16) & 1u);
  return (ux >> 16) | (uy & 0xffff0000u);
}
static __device__ __forceinline__ unsigned short f2bf_s(float x) {
  unsigned int ux = __builtin_bit_cast(unsigned int, x);
  ux += 0x7fffu + ((ux >> 16) & 1u);
  return (unsigned short)(ux >> 16);
}
static __device__ __forceinline__ bf16x8 make_afrag(float4 lo, float4 hi) {
  u32x4 p;
  p[0] = pack2bf(lo.x, lo.y);
  p[1] = pack2bf(lo.z, lo.w);
  p[2] = pack2bf(hi.x, hi.y);
  p[3] = pack2bf(hi.z, hi.w);
  return __builtin_bit_cast(bf16x8, p);
}

// ---- pass 0: per-node projections P = emb@W1[0:64] + b1, Q = emb@W1[64:128].
// (b1 folded into P: h = relu(P'+Q).) Rows stored in PERMUTED channel order
// pos p <- channel (p&3)*16+(p>>2) so each lane's 4 acc values are adjacent
// -> fully-coalesced 8-B stores.
__global__ __launch_bounds__(256) void node_proj(
    const float* __restrict__ emb,   // [N,64] f32
    const float* __restrict__ W1,    // [128,64] f32 row-major
    const float* __restrict__ b1,    // [64]
    u32x2* __restrict__ P,           // [N,16] 8-B units (permuted bf16 rows)
    u32x2* __restrict__ Q,
    int N, int ntiles)
{
  __shared__ unsigned short ls_w1t[64 * LDSTR];   // W1^T [n][k]
  const int tid  = threadIdx.x;
  const int wave = tid >> 6;
  const int lane = tid & 63;
  const int l15  = lane & 15;
  const int quad = lane >> 4;

  // Coalesced staging: consecutive lanes read consecutive W1 elements.
  for (int i = tid; i < 64 * 128; i += 256) {
    int k = i >> 6, n = i & 63;                    // W1[k][n], linear read
    ls_w1t[n * LDSTR + k] = f2bf_s(W1[i]);
  }
  __syncthreads();

  bf16x8 bfragP[4][2], bfragQ[4][2];
  float myb1[4];
  #pragma unroll
  for (int tn = 0; tn < 4; ++tn) {
    myb1[tn] = b1[tn * 16 + l15];
    #pragma unroll
    for (int s = 0; s < 2; ++s) {
      bfragP[tn][s] = *(const bf16x8*)&ls_w1t[(tn * 16 + l15) * LDSTR + s * 32 + quad * 8];
      bfragQ[tn][s] = *(const bf16x8*)&ls_w1t[(tn * 16 + l15) * LDSTR + 64 + s * 32 + quad * 8];
    }
  }

  for (int tile = blockIdx.x * 4 + wave; tile < ntiles; tile += gridDim.x * 4) {
    const int base = tile * 16;

    bf16x8 afr0, afr1;
    {
      int node = base + l15;
      node = (node < N) ? node : N - 1;
      const float* rp = emb + (long long)node * 64 + quad * 8;
      afr0 = make_afrag(*(const float4*)(rp),      *(const float4*)(rp + 4));
      afr1 = make_afrag(*(const float4*)(rp + 32), *(const float4*)(rp + 36));
    }

    f32x4 aP[4], aQ[4];
    #pragma unroll
    for (int tn = 0; tn < 4; ++tn) { aP[tn] = (f32x4){0,0,0,0}; aQ[tn] = (f32x4){0,0,0,0}; }
    #pragma unroll
    for (int tn = 0; tn < 4; ++tn) {
      aP[tn] = __builtin_amdgcn_mfma_f32_16x16x32_bf16(afr0, bfragP[tn][0], aP[tn], 0, 0, 0);
      aQ[tn] = __builtin_amdgcn_mfma_f32_16x16x32_bf16(afr0, bfragQ[tn][0], aQ[tn], 0, 0, 0);
      aP[tn] = __builtin_amdgcn_mfma_f32_16x16x32_bf16(afr1, bfragP[tn][1], aP[tn], 0, 0, 0);
      aQ[tn] = __builtin_amdgcn_mfma_f32_16x16x32_bf16(afr1, bfragQ[tn][1], aQ[tn], 0, 0, 0);
    }

    #pragma unroll
    for (int r = 0; r < 4; ++r) {
      const int m = base + quad * 4 + r;
      if (m < N) {
        u32x2 vp, vq;
        vp[0] = pack2bf(aP[0][r] + myb1[0], aP[1][r] + myb1[1]);
        vp[1] = pack2bf(aP[2][r] + myb1[2], aP[3][r] + myb1[3]);
        vq[0] = pack2bf(aQ[0][r], aQ[1][r]);
        vq[1] = pack2bf(aQ[2][r], aQ[3][r]);
        P[(long long)m * 16 + l15] = vp;
        Q[(long long)m * 16 + l15] = vq;
      }
    }
  }
}

// ---- main: streaming edge scorer, 4 edge-chunks in flight per wave.
// 8 lanes per edge (one full 128-B row per 8 lanes), zero LDS/MFMA.
// b1 pre-folded into P. Channel order permuted; W2 looked up through the
// permutation at setup (sum over channels is order-invariant).
__global__ __launch_bounds__(256) void edge_score(
    const unsigned short* __restrict__ P,   // [N,64] bf16 (permuted, +b1)
    const unsigned short* __restrict__ Q,
    const int*   __restrict__ src,
    const int*   __restrict__ dst,
    const float* __restrict__ W2,    // [64]
    const float* __restrict__ b2,
    float*       __restrict__ out,   // [E]
    int E)
{
  const int tid  = blockIdx.x * 256 + threadIdx.x;
  const int lane = threadIdx.x & 63;
  const int s    = lane & 7;          // sliver within row (8 bf16 = 16 B)
  const int g    = lane >> 3;         // edge-group within wave (0..7)
  const int wid  = tid >> 6;          // global wave id
  const int nwav = gridDim.x * 4;

  float w2v[8];
  #pragma unroll
  for (int j = 0; j < 8; ++j) {
    const int pos = s * 8 + j;
    const int ch  = (pos & 3) * 16 + (pos >> 2);
    w2v[j] = W2[ch];
  }
  const float b2v = b2[0];
  const int so16 = s * 8;             // short offset of this lane's sliver

#define DOT8(PV, QV, ACC)                                                     \
  {                                                                           \
    u32x4 pu = __builtin_bit_cast(u32x4, PV);                                 \
    u32x4 qu = __builtin_bit_cast(u32x4, QV);                                 \
    _Pragma("unroll")                                                         \
    for (int i = 0; i < 4; ++i) {                                             \
      float pl = __builtin_bit_cast(float, pu[i] << 16);                      \
      float ph = __builtin_bit_cast(float, pu[i] & 0xffff0000u);              \
      float ql = __builtin_bit_cast(float, qu[i] << 16);                      \
      float qh = __builtin_bit_cast(float, qu[i] & 0xffff0000u);              \
      float h0 = fmaxf(pl + ql, 0.f);                                         \
      float h1 = fmaxf(ph + qh, 0.f);                                         \
      ACC = __builtin_fmaf(h0, w2v[2 * i], ACC);                              \
      ACC = __builtin_fmaf(h1, w2v[2 * i + 1], ACC);                          \
    }                                                                         \
  }

  // 32 edges per wave per iteration: 4 independent chunks, 8 gathers in flight
  const int step = nwav * 32;
  for (int e0 = wid * 32; e0 < E; e0 += step) {
    const int eA = e0 + g;
    const int eB = e0 + 8 + g;
    const int eC = e0 + 16 + g;
    const int eD = e0 + 24 + g;
    const int eAc = (eA < E) ? eA : (E - 1);
    const int eBc = (eB < E) ? eB : (E - 1);
    const int eCc = (eC < E) ? eC : (E - 1);
    const int eDc = (eD < E) ? eD : (E - 1);
    const int siA = src[eAc], diA = dst[eAc];
    const int siB = src[eBc], diB = dst[eBc];
    const int siC = src[eCc], diC = dst[eCc];
    const int siD = src[eDc], diD = dst[eDc];

    const bf16x8 pvA = *(const bf16x8*)(P + (long long)siA * 64 + so16);
    const bf16x8 qvA = *(const bf16x8*)(Q + (long long)diA * 64 + so16);
    const bf16x8 pvB = *(const bf16x8*)(P + (long long)siB * 64 + so16);
    const bf16x8 qvB = *(const bf16x8*)(Q + (long long)diB * 64 + so16);
    const bf16x8 pvC = *(const bf16x8*)(P + (long long)siC * 64 + so16);
    const bf16x8 qvC = *(const bf16x8*)(Q + (long long)diC * 64 + so16);
    const bf16x8 pvD = *(const bf16x8*)(P + (long long)siD * 64 + so16);
    const bf16x8 qvD = *(const bf16x8*)(Q + (long long)diD * 64 + so16);

    float accA = 0.f, accB = 0.f, accC = 0.f, accD = 0.f;
    DOT8(pvA, qvA, accA);
    DOT8(pvB, qvB, accB);
    DOT8(pvC, qvC, accC);
    DOT8(pvD, qvD, accD);

    accA += __shfl_xor(accA, 1); accB += __shfl_xor(accB, 1);
    accC += __shfl_xor(accC, 1); accD += __shfl_xor(accD, 1);
    accA += __shfl_xor(accA, 2); accB += __shfl_xor(accB, 2);
    accC += __shfl_xor(accC, 2); accD += __shfl_xor(accD, 2);
    accA += __shfl_xor(accA, 4); accB += __shfl_xor(accB, 4);
    accC += __shfl_xor(accC, 4); accD += __shfl_xor(accD, 4);

    if (s == 0) {
      if (eA < E) out[eA] = accA + b2v;
      if (eB < E) out[eB] = accB + b2v;
      if (eC < E) out[eC] = accC + b2v;
      if (eD < E) out[eD] = accD + b2v;
    }
  }
#undef DOT8
}

// ---- fallback: f32 gathers + MFMA (no workspace) ----
__global__ __launch_bounds__(256) void edge_mlp_f32(
    const float* __restrict__ nodes_emb, const int* __restrict__ src,
    const int* __restrict__ dst, const float* __restrict__ W1,
    const float* __restrict__ b1, const float* __restrict__ W2,
    const float* __restrict__ b2, float* __restrict__ out, int E)
{
  __shared__ unsigned short ls_w1t[64 * LDSTR];
  __shared__ float ls_b1[64];
  __shared__ float ls_w2[64];
  const int tid = threadIdx.x, wave = tid >> 6, lane = tid & 63;
  const int l15 = lane & 15, quad = lane >> 4;
  for (int i = tid; i < 64 * 128; i += 256) {
    int n = i >> 7, k = i & 127;
    ls_w1t[n * LDSTR + k] = f2bf_s(W1[k * 64 + n]);
  }
  if (tid < 64) { ls_b1[tid] = b1[tid]; ls_w2[tid] = W2[tid]; }
  __syncthreads();
  bf16x8 bfrag[4][4];
  #pragma unroll
  for (int tn = 0; tn < 4; ++tn)
    #pragma unroll
    for (int s = 0; s < 4; ++s)
      bfrag[tn][s] = *(const bf16x8*)&ls_w1t[(tn * 16 + l15) * LDSTR + s * 32 + quad * 8];
  float myb1[4], myw2[4];
  #pragma unroll
  for (int tn = 0; tn < 4; ++tn) { myb1[tn] = ls_b1[tn*16+l15]; myw2[tn] = ls_w2[tn*16+l15]; }
  const float b2v = b2[0];
  const int wave_base = blockIdx.x * (TPW * 64) + wave * (TPW * 16);
  #pragma unroll 1
  for (int t = 0; t < TPW; ++t) {
    const int tile_base = wave_base + t * 16;
    if (tile_base >= E) break;
    const int e = tile_base + l15;
    const int si = src[e], di = dst[e];
    const float* srow = nodes_emb + (long long)si * 64 + quad * 8;
    const float* drow = nodes_emb + (long long)di * 64 + quad * 8;
    float4 v0 = *(const float4*)(srow),      v1 = *(const float4*)(srow + 4);
    float4 v2 = *(const float4*)(srow + 32), v3 = *(const float4*)(srow + 36);
    float4 v4 = *(const float4*)(drow),      v5 = *(const float4*)(drow + 4);
    float4 v6 = *(const float4*)(drow + 32), v7 = *(const float4*)(drow + 36);
    bf16x8 afr[4] = {make_afrag(v0,v1), make_afrag(v2,v3), make_afrag(v4,v5), make_afrag(v6,v7)};
    f32x4 acc[4];
    #pragma unroll
    for (int tn = 0; tn < 4; ++tn) acc[tn] = (f32x4){0.f,0.f,0.f,0.f};
    #pragma unroll
    for (int s = 0; s < 4; ++s)
      #pragma unroll
      for (int tn = 0; tn < 4; ++tn)
        acc[tn] = __builtin_amdgcn_mfma_f32_16x16x32_bf16(afr[s], bfrag[tn][s], acc[tn], 0, 0, 0);
    #pragma unroll
    for (int r = 0; r < 4; ++r) {
      float p = 0.f;
      #pragma unroll
      for (int tn = 0; tn < 4; ++tn) {
        float h = fmaxf(acc[tn][r] + myb1[tn], 0.f);
        p = __builtin_fmaf(h, myw2[tn], p);
      }
      p += __shfl_xor(p, 1); p += __shfl_xor(p, 2);
      p += __shfl_xor(p, 4); p += __shfl_xor(p, 8);
      if (l15 == 0) out[tile_base + quad * 4 + r] = p + b2v;
    }
  }
}

extern "C" void kernel_launch(void* const* d_in, const int* in_sizes, int n_in,
                              void* d_out, int out_size, void* d_ws, size_t ws_size,
                              hipStream_t stream) {
  const float* nodes_emb = (const float*)d_in[0];
  const int*   src       = (const int*)d_in[1];
  const int*   dst       = (const int*)d_in[2];
  const float* W1        = (const float*)d_in[3];
  const float* b1        = (const float*)d_in[4];
  const float* W2        = (const float*)d_in[5];
  const float* b2        = (const float*)d_in[6];
  float* out = (float*)d_out;

  const int E = in_sizes[1];
  const int nodes_elems = in_sizes[0];               // N * 64
  const int N = nodes_elems / 64;
  const size_t szP = (size_t)nodes_elems * 2;        // bf16 [N,64]
  const size_t need = szP * 2;                       // P + Q

  if (ws_size >= need) {
    u32x2* P = (u32x2*)d_ws;
    u32x2* Q = (u32x2*)((char*)d_ws + szP);
    const int ntiles = (N + 15) / 16;
    hipLaunchKernelGGL(node_proj, dim3(1024), dim3(256), 0, stream,
                       nodes_emb, W1, b1, P, Q, N, ntiles);
    hipLaunchKernelGGL(edge_score, dim3(4096), dim3(256), 0, stream,
                       (const unsigned short*)P, (const unsigned short*)Q,
                       src, dst, W2, b2, out, E);
  } else {
    const int epb = TPW * 64;
    const int blocks = (E + epb - 1) / epb;
    hipLaunchKernelGGL(edge_mlp_f32, dim3(blocks), dim3(256), 0, stream,
                       nodes_emb, src, dst, W1, b1, W2, b2, out, E);
  }
}